// Round 7
// baseline (124.307 us; speedup 1.0000x reference)
//
#include <hip/hip_runtime.h>
#include <hip/hip_bf16.h>

#define NUM_CLASSES 200
#define NF 128
#define NP 2000
#define HW 196
#define MPAD 208        // 13 * 16
#define NB 64
#define EPSV 1e-4f
#define TROW 17         // fp32 staging tile row stride (floats)

typedef __attribute__((ext_vector_type(8))) short short8;   // 8 bf16 = 4 VGPR
typedef __attribute__((ext_vector_type(4))) float f32x4;

static __device__ __forceinline__ unsigned short f2bf(float x) {
    __hip_bfloat16 h = __float2bfloat16(x);
    return __builtin_bit_cast(unsigned short, h);
}

// async global->LDS DMA, 16 B per lane (wave-uniform base + lane*16 layout)
static __device__ __forceinline__ void async_copy16(const void* g, void* l) {
    __builtin_amdgcn_global_load_lds(
        (const __attribute__((address_space(1))) unsigned int*)g,
        (__attribute__((address_space(3))) unsigned int*)l,
        16, 0, 0);
}

// ---- kernel 0: transpose+convert f -> fT (bf16, XOR-swizzled 16B units) ------
// grid 832 = 64 n x 13 hw-tiles. Also computes exact fp32 xsq inline.
__global__ __launch_bounds__(256) void ktrans(const float* __restrict__ f,
                                              unsigned short* __restrict__ fT,
                                              float* __restrict__ xsq) {
    __shared__ float tile[NF * TROW];
    const int b  = blockIdx.x;
    const int n  = b / 13;
    const int mt = b % 13;
    const int t  = threadIdx.x;
    const int hw0 = mt * 16;

    {
        int kb  = t >> 2;             // 0..63
        int hwl = (t & 3) * 4;        // 0,4,8,12
        float4 v0 = make_float4(0.f, 0.f, 0.f, 0.f), v1 = v0;
        if (hw0 + hwl + 4 <= HW) {    // HW=196 multiple of 4
            v0 = *(const float4*)(f + ((size_t)n * NF + kb) * HW + hw0 + hwl);
            v1 = *(const float4*)(f + ((size_t)n * NF + kb + 64) * HW + hw0 + hwl);
        }
        tile[kb * TROW + hwl + 0] = v0.x;
        tile[kb * TROW + hwl + 1] = v0.y;
        tile[kb * TROW + hwl + 2] = v0.z;
        tile[kb * TROW + hwl + 3] = v0.w;
        tile[(kb + 64) * TROW + hwl + 0] = v1.x;
        tile[(kb + 64) * TROW + hwl + 1] = v1.y;
        tile[(kb + 64) * TROW + hwl + 2] = v1.z;
        tile[(kb + 64) * TROW + hwl + 3] = v1.w;
    }
    __syncthreads();
    {
        int hwl2 = t >> 4;            // 0..15  (hw within tile)
        int kg   = t & 15;            // 0..15  (8-k group)
        float xp = 0.f;
        unsigned short u[8];
        #pragma unroll
        for (int j = 0; j < 8; ++j) {
            float val = tile[(kg * 8 + j) * TROW + hwl2];
            xp += val * val;
            u[j] = f2bf(val);
        }
        // pre-swizzled global store: unit kg of row (hw) lands at kg^hwl2
        ((uint4*)fT)[((size_t)n * MPAD + hw0 + hwl2) * 16 + (kg ^ hwl2)] = *(uint4*)u;
        xp += __shfl_xor(xp, 1, 64);
        xp += __shfl_xor(xp, 2, 64);
        xp += __shfl_xor(xp, 4, 64);
        xp += __shfl_xor(xp, 8, 64);
        if (kg == 0 && hw0 + hwl2 < HW) xsq[n * HW + hw0 + hwl2] = xp;
    }
}

// ---- kernel 1: MFMA distance + min + fused sim -------------------------------
// grid (64 n, 8 p-tiles of 256) [n fastest -> same-n blocks share an XCD L2].
// LDS = 52 KB B-buffer only -> 3 blocks/CU. fT staged via async DMA; A-frags +
// exact psq from fp32 protos overlap the DMA. Writes min_dist + simT[p][n].
__global__ __launch_bounds__(256, 3) void kdist(const float* __restrict__ protos,
                                                const unsigned short* __restrict__ fT,
                                                const float* __restrict__ xsq,
                                                float* __restrict__ min_out,
                                                float* __restrict__ simT) {
    __shared__ __align__(16) unsigned short sf[MPAD * NF];   // 53,248 B

    const int n    = blockIdx.x;
    const int pt   = blockIdx.y;
    const int t    = threadIdx.x;
    const int wave = t >> 6;
    const int lane = t & 63;
    const int row  = lane & 15;
    const int quad = lane >> 4;
    const int pb   = pt * 256 + wave * 64;

    // ---- issue async DMA first: 52 chunks of 1 KB (13 per wave) --------------
    {
        const char* fb = (const char*)(fT + (size_t)n * MPAD * NF);
        #pragma unroll
        for (int i = 0; i < 13; ++i) {
            int off = (i * 4 + wave) * 1024 + lane * 16;
            async_copy16(fb + off, (char*)sf + off);
        }
    }

    // ---- A frags from fp32 protos (cvt bf16) + exact fp32 psq (overlaps DMA) -
    short8 A[4][4];
    float psum[4];
    #pragma unroll
    for (int g = 0; g < 4; ++g) {
        int p = pb + g * 16 + row;
        const float* ap = protos + (size_t)(p < NP ? p : NP - 1) * NF + quad * 8;
        psum[g] = 0.f;
        #pragma unroll
        for (int kk = 0; kk < 4; ++kk) {
            float4 v0 = *(const float4*)(ap + kk * 32);
            float4 v1 = *(const float4*)(ap + kk * 32 + 4);
            psum[g] += v0.x * v0.x + v0.y * v0.y + v0.z * v0.z + v0.w * v0.w
                     + v1.x * v1.x + v1.y * v1.y + v1.z * v1.z + v1.w * v1.w;
            short8 a;
            a[0] = (short)f2bf(v0.x); a[1] = (short)f2bf(v0.y);
            a[2] = (short)f2bf(v0.z); a[3] = (short)f2bf(v0.w);
            a[4] = (short)f2bf(v1.x); a[5] = (short)f2bf(v1.y);
            a[6] = (short)f2bf(v1.z); a[7] = (short)f2bf(v1.w);
            A[g][kk] = a;
        }
        psum[g] += __shfl_xor(psum[g], 16, 64);
        psum[g] += __shfl_xor(psum[g], 32, 64);
    }

    // ---- xsq preload (L2-hot, per-lane column) -------------------------------
    float xv[13];
    {
        const float* xs_n = xsq + n * HW;
        #pragma unroll
        for (int mt = 0; mt < 13; ++mt) {
            int hw = mt * 16 + row;
            xv[mt] = (hw < HW) ? xs_n[hw] : 3.0e38f;
        }
    }

    __syncthreads();   // drains the DMA (vmcnt) + barrier

    // ---- MFMA loop -----------------------------------------------------------
    float runmin[4][4];
    #pragma unroll
    for (int g = 0; g < 4; ++g)
        #pragma unroll
        for (int r = 0; r < 4; ++r) runmin[g][r] = 3.0e38f;

    const short8* sfv = (const short8*)sf;   // 16 units per 256-B row
    for (int mt = 0; mt < 13; ++mt) {
        const int base = (mt * 16 + row) * 16;
        short8 b0 = sfv[base + ((quad + 0)  ^ row)];
        short8 b1 = sfv[base + ((quad + 4)  ^ row)];
        short8 b2 = sfv[base + ((quad + 8)  ^ row)];
        short8 b3 = sfv[base + ((quad + 12) ^ row)];

        #pragma unroll
        for (int g = 0; g < 4; ++g) {
            f32x4 acc = {0.f, 0.f, 0.f, 0.f};
            acc = __builtin_amdgcn_mfma_f32_16x16x32_bf16(A[g][0], b0, acc, 0, 0, 0);
            acc = __builtin_amdgcn_mfma_f32_16x16x32_bf16(A[g][1], b1, acc, 0, 0, 0);
            acc = __builtin_amdgcn_mfma_f32_16x16x32_bf16(A[g][2], b2, acc, 0, 0, 0);
            acc = __builtin_amdgcn_mfma_f32_16x16x32_bf16(A[g][3], b3, acc, 0, 0, 0);
            #pragma unroll
            for (int r = 0; r < 4; ++r)
                runmin[g][r] = fminf(runmin[g][r], xv[mt] - 2.f * acc[r]);
        }
    }

    // ---- min over the 16 D-columns, epilogue ---------------------------------
    #pragma unroll
    for (int g = 0; g < 4; ++g) {
        #pragma unroll
        for (int off = 1; off < 16; off <<= 1)
            #pragma unroll
            for (int r = 0; r < 4; ++r)
                runmin[g][r] = fminf(runmin[g][r], __shfl_xor(runmin[g][r], off, 64));
        #pragma unroll
        for (int r = 0; r < 4; ++r) {
            float psq_sel = __shfl(psum[g], 20 * quad + r, 64);
            int p = pb + g * 16 + quad * 4 + r;
            if (row == 0 && p < NP) {
                float m = fmaxf(runmin[g][r] + psq_sel, 0.f);
                min_out[(size_t)n * NP + p] = m;
                simT[(size_t)p * NB + n] = logf((m + 1.f) / (m + EPSV));
            }
        }
    }
}

// ---- kernel 2: logits[n][c] = sum_p simT[p][n] * W[c][p] ---------------------
// one block per class; lanes = n -> W loads are wave-uniform (scalar), simT
// loads coalesced. No shuffles.
__global__ __launch_bounds__(256) void klogits(const float* __restrict__ simT,
                                               const float* __restrict__ W,
                                               float* __restrict__ logits) {
    __shared__ float part[4][NB];
    const int c    = blockIdx.x;
    const int wave = threadIdx.x >> 6;
    const int lane = threadIdx.x & 63;

    const float* wr = W + (size_t)c * NP;
    float acc = 0.f;
    #pragma unroll 10
    for (int i = 0; i < 500; ++i) {
        int p = wave + 4 * i;
        acc = fmaf(wr[p], simT[(size_t)p * NB + lane], acc);
    }
    part[wave][lane] = acc;
    __syncthreads();
    if (wave == 0) {
        float v = part[0][lane] + part[1][lane] + part[2][lane] + part[3][lane];
        logits[(size_t)lane * NUM_CLASSES + c] = v;
    }
}

extern "C" void kernel_launch(void* const* d_in, const int* in_sizes, int n_in,
                              void* d_out, int out_size, void* d_ws, size_t ws_size,
                              hipStream_t stream) {
    const float* f      = (const float*)d_in[0];  // 64x128x14x14
    const float* protos = (const float*)d_in[1];  // 2000x128
    const float* W      = (const float*)d_in[2];  // 200x2000

    float* logits   = (float*)d_out;
    float* min_dist = (float*)d_out + NB * NUM_CLASSES;

    float* simT = (float*)d_ws;                          // 2000*64 f32
    float* xsq  = simT + (size_t)NP * NB;                // 64*196 f32
    unsigned short* fT = (unsigned short*)(xsq + NB * HW + 32);  // 64*208*128 bf16

    ktrans<<<832, 256, 0, stream>>>(f, fT, xsq);
    kdist<<<dim3(NB, 8), 256, 0, stream>>>(protos, fT, xsq, min_dist, simT);
    klogits<<<NUM_CLASSES, 256, 0, stream>>>(simT, W, logits);
}

// Round 8
// 123.061 us; speedup vs baseline: 1.0101x; 1.0101x over previous
//
#include <hip/hip_runtime.h>
#include <hip/hip_bf16.h>

#define NUM_CLASSES 200
#define NF 128
#define NP 2000
#define HW 196
#define MPAD 208        // 13 * 16
#define NB 64
#define EPSV 1e-4f
#define TROW 17         // fp32 staging tile row stride (floats)

typedef __attribute__((ext_vector_type(8))) short short8;   // 8 bf16 = 4 VGPR
typedef __attribute__((ext_vector_type(4))) float f32x4;

static __device__ __forceinline__ unsigned short f2bf(float x) {
    __hip_bfloat16 h = __float2bfloat16(x);
    return __builtin_bit_cast(unsigned short, h);
}

// async global->LDS DMA, 16 B per lane.
// lds_base MUST be wave-uniform: HW writes lds_base + lane*16 (m104/m108).
static __device__ __forceinline__ void async_copy16(const void* g, void* lds_base) {
    __builtin_amdgcn_global_load_lds(
        (const __attribute__((address_space(1))) unsigned int*)g,
        (__attribute__((address_space(3))) unsigned int*)lds_base,
        16, 0, 0);
}

// ---- kernel 0: transpose+convert f -> fT (bf16, XOR-swizzled 16B units) ------
// grid 832 = 64 n x 13 hw-tiles. Also computes exact fp32 xsq inline.
__global__ __launch_bounds__(256) void ktrans(const float* __restrict__ f,
                                              unsigned short* __restrict__ fT,
                                              float* __restrict__ xsq) {
    __shared__ float tile[NF * TROW];
    const int b  = blockIdx.x;
    const int n  = b / 13;
    const int mt = b % 13;
    const int t  = threadIdx.x;
    const int hw0 = mt * 16;

    {
        int kb  = t >> 2;             // 0..63
        int hwl = (t & 3) * 4;        // 0,4,8,12
        float4 v0 = make_float4(0.f, 0.f, 0.f, 0.f), v1 = v0;
        if (hw0 + hwl + 4 <= HW) {    // HW=196 multiple of 4
            v0 = *(const float4*)(f + ((size_t)n * NF + kb) * HW + hw0 + hwl);
            v1 = *(const float4*)(f + ((size_t)n * NF + kb + 64) * HW + hw0 + hwl);
        }
        tile[kb * TROW + hwl + 0] = v0.x;
        tile[kb * TROW + hwl + 1] = v0.y;
        tile[kb * TROW + hwl + 2] = v0.z;
        tile[kb * TROW + hwl + 3] = v0.w;
        tile[(kb + 64) * TROW + hwl + 0] = v1.x;
        tile[(kb + 64) * TROW + hwl + 1] = v1.y;
        tile[(kb + 64) * TROW + hwl + 2] = v1.z;
        tile[(kb + 64) * TROW + hwl + 3] = v1.w;
    }
    __syncthreads();
    {
        int hwl2 = t >> 4;            // 0..15  (hw within tile)
        int kg   = t & 15;            // 0..15  (8-k group)
        float xp = 0.f;
        unsigned short u[8];
        #pragma unroll
        for (int j = 0; j < 8; ++j) {
            float val = tile[(kg * 8 + j) * TROW + hwl2];
            xp += val * val;
            u[j] = f2bf(val);
        }
        // pre-swizzled global store: unit kg of row (hw) lands at kg^hwl2
        ((uint4*)fT)[((size_t)n * MPAD + hw0 + hwl2) * 16 + (kg ^ hwl2)] = *(uint4*)u;
        xp += __shfl_xor(xp, 1, 64);
        xp += __shfl_xor(xp, 2, 64);
        xp += __shfl_xor(xp, 4, 64);
        xp += __shfl_xor(xp, 8, 64);
        if (kg == 0 && hw0 + hwl2 < HW) xsq[n * HW + hw0 + hwl2] = xp;
    }
}

// ---- kernel 1: MFMA distance + min + fused sim -------------------------------
// grid (64 n, 8 p-tiles of 256) [n fastest -> same-n blocks share an XCD L2].
// LDS = 52 KB B-buffer only -> 3 blocks/CU. fT staged via async DMA (uniform
// LDS base per chunk); A-frags + exact psq from fp32 protos overlap the DMA.
__global__ __launch_bounds__(256, 3) void kdist(const float* __restrict__ protos,
                                                const unsigned short* __restrict__ fT,
                                                const float* __restrict__ xsq,
                                                float* __restrict__ min_out,
                                                float* __restrict__ simT) {
    __shared__ __align__(16) unsigned short sf[MPAD * NF];   // 53,248 B

    const int n    = blockIdx.x;
    const int pt   = blockIdx.y;
    const int t    = threadIdx.x;
    const int wave = t >> 6;
    const int lane = t & 63;
    const int row  = lane & 15;
    const int quad = lane >> 4;
    const int pb   = pt * 256 + wave * 64;

    // ---- issue async DMA first: 52 chunks of 1 KB (13 per wave) --------------
    // LDS base is wave-uniform (i, wave only); HW adds lane*16.
    {
        const char* fb = (const char*)(fT + (size_t)n * MPAD * NF);
        char* lb = (char*)sf;
        #pragma unroll
        for (int i = 0; i < 13; ++i) {
            const int chunk = (i * 4 + wave) * 1024;
            async_copy16(fb + chunk + lane * 16, lb + chunk);
        }
    }

    // ---- A frags from fp32 protos (cvt bf16) + exact fp32 psq (overlaps DMA) -
    short8 A[4][4];
    float psum[4];
    #pragma unroll
    for (int g = 0; g < 4; ++g) {
        int p = pb + g * 16 + row;
        const float* ap = protos + (size_t)(p < NP ? p : NP - 1) * NF + quad * 8;
        psum[g] = 0.f;
        #pragma unroll
        for (int kk = 0; kk < 4; ++kk) {
            float4 v0 = *(const float4*)(ap + kk * 32);
            float4 v1 = *(const float4*)(ap + kk * 32 + 4);
            psum[g] += v0.x * v0.x + v0.y * v0.y + v0.z * v0.z + v0.w * v0.w
                     + v1.x * v1.x + v1.y * v1.y + v1.z * v1.z + v1.w * v1.w;
            short8 a;
            a[0] = (short)f2bf(v0.x); a[1] = (short)f2bf(v0.y);
            a[2] = (short)f2bf(v0.z); a[3] = (short)f2bf(v0.w);
            a[4] = (short)f2bf(v1.x); a[5] = (short)f2bf(v1.y);
            a[6] = (short)f2bf(v1.z); a[7] = (short)f2bf(v1.w);
            A[g][kk] = a;
        }
        psum[g] += __shfl_xor(psum[g], 16, 64);
        psum[g] += __shfl_xor(psum[g], 32, 64);
    }

    // ---- xsq preload (L2-hot, per-lane column) -------------------------------
    float xv[13];
    {
        const float* xs_n = xsq + n * HW;
        #pragma unroll
        for (int mt = 0; mt < 13; ++mt) {
            int hw = mt * 16 + row;
            xv[mt] = (hw < HW) ? xs_n[hw] : 3.0e38f;
        }
    }

    __syncthreads();   // drains the DMA (vmcnt) + barrier

    // ---- MFMA loop -----------------------------------------------------------
    float runmin[4][4];
    #pragma unroll
    for (int g = 0; g < 4; ++g)
        #pragma unroll
        for (int r = 0; r < 4; ++r) runmin[g][r] = 3.0e38f;

    const short8* sfv = (const short8*)sf;   // 16 units per 256-B row
    for (int mt = 0; mt < 13; ++mt) {
        const int base = (mt * 16 + row) * 16;
        short8 b0 = sfv[base + ((quad + 0)  ^ row)];
        short8 b1 = sfv[base + ((quad + 4)  ^ row)];
        short8 b2 = sfv[base + ((quad + 8)  ^ row)];
        short8 b3 = sfv[base + ((quad + 12) ^ row)];

        #pragma unroll
        for (int g = 0; g < 4; ++g) {
            f32x4 acc = {0.f, 0.f, 0.f, 0.f};
            acc = __builtin_amdgcn_mfma_f32_16x16x32_bf16(A[g][0], b0, acc, 0, 0, 0);
            acc = __builtin_amdgcn_mfma_f32_16x16x32_bf16(A[g][1], b1, acc, 0, 0, 0);
            acc = __builtin_amdgcn_mfma_f32_16x16x32_bf16(A[g][2], b2, acc, 0, 0, 0);
            acc = __builtin_amdgcn_mfma_f32_16x16x32_bf16(A[g][3], b3, acc, 0, 0, 0);
            #pragma unroll
            for (int r = 0; r < 4; ++r)
                runmin[g][r] = fminf(runmin[g][r], xv[mt] - 2.f * acc[r]);
        }
    }

    // ---- min over the 16 D-columns, epilogue ---------------------------------
    #pragma unroll
    for (int g = 0; g < 4; ++g) {
        #pragma unroll
        for (int off = 1; off < 16; off <<= 1)
            #pragma unroll
            for (int r = 0; r < 4; ++r)
                runmin[g][r] = fminf(runmin[g][r], __shfl_xor(runmin[g][r], off, 64));
        #pragma unroll
        for (int r = 0; r < 4; ++r) {
            float psq_sel = __shfl(psum[g], 20 * quad + r, 64);
            int p = pb + g * 16 + quad * 4 + r;
            if (row == 0 && p < NP) {
                float m = fmaxf(runmin[g][r] + psq_sel, 0.f);
                min_out[(size_t)n * NP + p] = m;
                simT[(size_t)p * NB + n] = logf((m + 1.f) / (m + EPSV));
            }
        }
    }
}

// ---- kernel 2: logits[n][c] = sum_p simT[p][n] * W[c][p] ---------------------
// one block per class; lanes = n -> W loads are wave-uniform (scalar), simT
// loads coalesced. No shuffles.
__global__ __launch_bounds__(256) void klogits(const float* __restrict__ simT,
                                               const float* __restrict__ W,
                                               float* __restrict__ logits) {
    __shared__ float part[4][NB];
    const int c    = blockIdx.x;
    const int wave = threadIdx.x >> 6;
    const int lane = threadIdx.x & 63;

    const float* wr = W + (size_t)c * NP;
    float acc = 0.f;
    #pragma unroll 10
    for (int i = 0; i < 500; ++i) {
        int p = wave + 4 * i;
        acc = fmaf(wr[p], simT[(size_t)p * NB + lane], acc);
    }
    part[wave][lane] = acc;
    __syncthreads();
    if (wave == 0) {
        float v = part[0][lane] + part[1][lane] + part[2][lane] + part[3][lane];
        logits[(size_t)lane * NUM_CLASSES + c] = v;
    }
}

extern "C" void kernel_launch(void* const* d_in, const int* in_sizes, int n_in,
                              void* d_out, int out_size, void* d_ws, size_t ws_size,
                              hipStream_t stream) {
    const float* f      = (const float*)d_in[0];  // 64x128x14x14
    const float* protos = (const float*)d_in[1];  // 2000x128
    const float* W      = (const float*)d_in[2];  // 200x2000

    float* logits   = (float*)d_out;
    float* min_dist = (float*)d_out + NB * NUM_CLASSES;

    float* simT = (float*)d_ws;                          // 2000*64 f32
    float* xsq  = simT + (size_t)NP * NB;                // 64*196 f32
    unsigned short* fT = (unsigned short*)(xsq + NB * HW + 32);  // 64*208*128 bf16

    ktrans<<<832, 256, 0, stream>>>(f, fT, xsq);
    kdist<<<dim3(NB, 8), 256, 0, stream>>>(protos, fT, xsq, min_dist, simT);
    klogits<<<NUM_CLASSES, 256, 0, stream>>>(simT, W, logits);
}

// Round 9
// 103.469 us; speedup vs baseline: 1.2014x; 1.1893x over previous
//
#include <hip/hip_runtime.h>
#include <hip/hip_bf16.h>

#define NUM_CLASSES 200
#define NF 128
#define NP 2000
#define HW 196
#define MPAD 208        // 13 * 16
#define NB 64
#define EPSV 1e-4f
#define TROW 17         // fp32 staging tile row stride (floats)

typedef __attribute__((ext_vector_type(8))) short short8;   // 8 bf16 = 4 VGPR
typedef __attribute__((ext_vector_type(4))) float f32x4;

static __device__ __forceinline__ unsigned short f2bf(float x) {
    __hip_bfloat16 h = __float2bfloat16(x);
    return __builtin_bit_cast(unsigned short, h);
}

// async global->LDS DMA, 16 B per lane.
// lds_base MUST be wave-uniform: HW writes lds_base + lane*16 (m104/m108).
static __device__ __forceinline__ void async_copy16(const void* g, void* lds_base) {
    __builtin_amdgcn_global_load_lds(
        (const __attribute__((address_space(1))) unsigned int*)g,
        (__attribute__((address_space(3))) unsigned int*)lds_base,
        16, 0, 0);
}

// ---- kernel 0: transpose+convert f -> fT (bf16, XOR-swizzled 16B units) ------
// grid 832 = 64 n x 13 hw-tiles. Also computes exact fp32 xsq inline.
__global__ __launch_bounds__(256) void ktrans(const float* __restrict__ f,
                                              unsigned short* __restrict__ fT,
                                              float* __restrict__ xsq) {
    __shared__ float tile[NF * TROW];
    const int b  = blockIdx.x;
    const int n  = b / 13;
    const int mt = b % 13;
    const int t  = threadIdx.x;
    const int hw0 = mt * 16;

    {
        int kb  = t >> 2;             // 0..63
        int hwl = (t & 3) * 4;        // 0,4,8,12
        float4 v0 = make_float4(0.f, 0.f, 0.f, 0.f), v1 = v0;
        if (hw0 + hwl + 4 <= HW) {    // HW=196 multiple of 4
            v0 = *(const float4*)(f + ((size_t)n * NF + kb) * HW + hw0 + hwl);
            v1 = *(const float4*)(f + ((size_t)n * NF + kb + 64) * HW + hw0 + hwl);
        }
        tile[kb * TROW + hwl + 0] = v0.x;
        tile[kb * TROW + hwl + 1] = v0.y;
        tile[kb * TROW + hwl + 2] = v0.z;
        tile[kb * TROW + hwl + 3] = v0.w;
        tile[(kb + 64) * TROW + hwl + 0] = v1.x;
        tile[(kb + 64) * TROW + hwl + 1] = v1.y;
        tile[(kb + 64) * TROW + hwl + 2] = v1.z;
        tile[(kb + 64) * TROW + hwl + 3] = v1.w;
    }
    __syncthreads();
    {
        int hwl2 = t >> 4;            // 0..15  (hw within tile)
        int kg   = t & 15;            // 0..15  (8-k group)
        float xp = 0.f;
        unsigned short u[8];
        #pragma unroll
        for (int j = 0; j < 8; ++j) {
            float val = tile[(kg * 8 + j) * TROW + hwl2];
            xp += val * val;
            u[j] = f2bf(val);
        }
        // pre-swizzled global store: unit kg of row (hw) lands at kg^hwl2
        ((uint4*)fT)[((size_t)n * MPAD + hw0 + hwl2) * 16 + (kg ^ hwl2)] = *(uint4*)u;
        xp += __shfl_xor(xp, 1, 64);
        xp += __shfl_xor(xp, 2, 64);
        xp += __shfl_xor(xp, 4, 64);
        xp += __shfl_xor(xp, 8, 64);
        if (kg == 0 && hw0 + hwl2 < HW) xsq[n * HW + hw0 + hwl2] = xp;
    }
}

// ---- kernel 1: MFMA distance + min + fused sim -------------------------------
// grid (64 n, 8 p-tiles of 256) [n fastest -> same-n blocks share an XCD L2].
// LDS = 52 KB B-buffer only. fT staged via async DMA (uniform LDS base per
// chunk); A-frags + exact psq from fp32 protos overlap the DMA.
// NOTE: (256,2) not (256,3) — 3 waves/EU caps VGPR budget at ~170 and spills
// the A-frags to scratch (R7/R8: WRITE_SIZE 65.8 MB, 49 us).
__global__ __launch_bounds__(256, 2) void kdist(const float* __restrict__ protos,
                                                const unsigned short* __restrict__ fT,
                                                const float* __restrict__ xsq,
                                                float* __restrict__ min_out,
                                                float* __restrict__ simT) {
    __shared__ __align__(16) unsigned short sf[MPAD * NF];   // 53,248 B

    const int n    = blockIdx.x;
    const int pt   = blockIdx.y;
    const int t    = threadIdx.x;
    const int wave = t >> 6;
    const int lane = t & 63;
    const int row  = lane & 15;
    const int quad = lane >> 4;
    const int pb   = pt * 256 + wave * 64;

    // ---- issue async DMA first: 52 chunks of 1 KB (13 per wave) --------------
    // LDS base is wave-uniform (i, wave only); HW adds lane*16.
    {
        const char* fb = (const char*)(fT + (size_t)n * MPAD * NF);
        char* lb = (char*)sf;
        #pragma unroll
        for (int i = 0; i < 13; ++i) {
            const int chunk = (i * 4 + wave) * 1024;
            async_copy16(fb + chunk + lane * 16, lb + chunk);
        }
    }

    // ---- A frags from fp32 protos (cvt bf16) + exact fp32 psq (overlaps DMA) -
    short8 A[4][4];
    float psum[4];
    #pragma unroll
    for (int g = 0; g < 4; ++g) {
        int p = pb + g * 16 + row;
        const float* ap = protos + (size_t)(p < NP ? p : NP - 1) * NF + quad * 8;
        psum[g] = 0.f;
        #pragma unroll
        for (int kk = 0; kk < 4; ++kk) {
            float4 v0 = *(const float4*)(ap + kk * 32);
            float4 v1 = *(const float4*)(ap + kk * 32 + 4);
            psum[g] += v0.x * v0.x + v0.y * v0.y + v0.z * v0.z + v0.w * v0.w
                     + v1.x * v1.x + v1.y * v1.y + v1.z * v1.z + v1.w * v1.w;
            short8 a;
            a[0] = (short)f2bf(v0.x); a[1] = (short)f2bf(v0.y);
            a[2] = (short)f2bf(v0.z); a[3] = (short)f2bf(v0.w);
            a[4] = (short)f2bf(v1.x); a[5] = (short)f2bf(v1.y);
            a[6] = (short)f2bf(v1.z); a[7] = (short)f2bf(v1.w);
            A[g][kk] = a;
        }
        psum[g] += __shfl_xor(psum[g], 16, 64);
        psum[g] += __shfl_xor(psum[g], 32, 64);
    }

    // ---- xsq preload (L2-hot, per-lane column) -------------------------------
    float xv[13];
    {
        const float* xs_n = xsq + n * HW;
        #pragma unroll
        for (int mt = 0; mt < 13; ++mt) {
            int hw = mt * 16 + row;
            xv[mt] = (hw < HW) ? xs_n[hw] : 3.0e38f;
        }
    }

    __syncthreads();   // drains the DMA (vmcnt) + barrier

    // ---- MFMA loop -----------------------------------------------------------
    float runmin[4][4];
    #pragma unroll
    for (int g = 0; g < 4; ++g)
        #pragma unroll
        for (int r = 0; r < 4; ++r) runmin[g][r] = 3.0e38f;

    const short8* sfv = (const short8*)sf;   // 16 units per 256-B row
    for (int mt = 0; mt < 13; ++mt) {
        const int base = (mt * 16 + row) * 16;
        short8 b0 = sfv[base + ((quad + 0)  ^ row)];
        short8 b1 = sfv[base + ((quad + 4)  ^ row)];
        short8 b2 = sfv[base + ((quad + 8)  ^ row)];
        short8 b3 = sfv[base + ((quad + 12) ^ row)];

        #pragma unroll
        for (int g = 0; g < 4; ++g) {
            f32x4 acc = {0.f, 0.f, 0.f, 0.f};
            acc = __builtin_amdgcn_mfma_f32_16x16x32_bf16(A[g][0], b0, acc, 0, 0, 0);
            acc = __builtin_amdgcn_mfma_f32_16x16x32_bf16(A[g][1], b1, acc, 0, 0, 0);
            acc = __builtin_amdgcn_mfma_f32_16x16x32_bf16(A[g][2], b2, acc, 0, 0, 0);
            acc = __builtin_amdgcn_mfma_f32_16x16x32_bf16(A[g][3], b3, acc, 0, 0, 0);
            #pragma unroll
            for (int r = 0; r < 4; ++r)
                runmin[g][r] = fminf(runmin[g][r], xv[mt] - 2.f * acc[r]);
        }
    }

    // ---- min over the 16 D-columns, epilogue ---------------------------------
    #pragma unroll
    for (int g = 0; g < 4; ++g) {
        #pragma unroll
        for (int off = 1; off < 16; off <<= 1)
            #pragma unroll
            for (int r = 0; r < 4; ++r)
                runmin[g][r] = fminf(runmin[g][r], __shfl_xor(runmin[g][r], off, 64));
        #pragma unroll
        for (int r = 0; r < 4; ++r) {
            float psq_sel = __shfl(psum[g], 20 * quad + r, 64);
            int p = pb + g * 16 + quad * 4 + r;
            if (row == 0 && p < NP) {
                float m = fmaxf(runmin[g][r] + psq_sel, 0.f);
                min_out[(size_t)n * NP + p] = m;
                simT[(size_t)p * NB + n] = logf((m + 1.f) / (m + EPSV));
            }
        }
    }
}

// ---- kernel 2: logits[n][c] = sum_p simT[p][n] * W[c][p] ---------------------
// one block per class; lanes = n -> W loads are wave-uniform (scalar), simT
// loads coalesced. No shuffles.
__global__ __launch_bounds__(256) void klogits(const float* __restrict__ simT,
                                               const float* __restrict__ W,
                                               float* __restrict__ logits) {
    __shared__ float part[4][NB];
    const int c    = blockIdx.x;
    const int wave = threadIdx.x >> 6;
    const int lane = threadIdx.x & 63;

    const float* wr = W + (size_t)c * NP;
    float acc = 0.f;
    #pragma unroll 10
    for (int i = 0; i < 500; ++i) {
        int p = wave + 4 * i;
        acc = fmaf(wr[p], simT[(size_t)p * NB + lane], acc);
    }
    part[wave][lane] = acc;
    __syncthreads();
    if (wave == 0) {
        float v = part[0][lane] + part[1][lane] + part[2][lane] + part[3][lane];
        logits[(size_t)lane * NUM_CLASSES + c] = v;
    }
}

extern "C" void kernel_launch(void* const* d_in, const int* in_sizes, int n_in,
                              void* d_out, int out_size, void* d_ws, size_t ws_size,
                              hipStream_t stream) {
    const float* f      = (const float*)d_in[0];  // 64x128x14x14
    const float* protos = (const float*)d_in[1];  // 2000x128
    const float* W      = (const float*)d_in[2];  // 200x2000

    float* logits   = (float*)d_out;
    float* min_dist = (float*)d_out + NB * NUM_CLASSES;

    float* simT = (float*)d_ws;                          // 2000*64 f32
    float* xsq  = simT + (size_t)NP * NB;                // 64*196 f32
    unsigned short* fT = (unsigned short*)(xsq + NB * HW + 32);  // 64*208*128 bf16

    ktrans<<<832, 256, 0, stream>>>(f, fT, xsq);
    kdist<<<dim3(NB, 8), 256, 0, stream>>>(protos, fT, xsq, min_dist, simT);
    klogits<<<NUM_CLASSES, 256, 0, stream>>>(simT, W, logits);
}